// Round 2
// baseline (12860.130 us; speedup 1.0000x reference)
//
#include <hip/hip_runtime.h>
#include <cstdint>

// ---------------- bf16 helpers ----------------
__device__ __forceinline__ float b2f(unsigned short u) {
    unsigned int t = ((unsigned int)u) << 16;
    float f;
    __builtin_memcpy(&f, &t, 4);
    return f;
}
__device__ __forceinline__ unsigned short f2b(float f) {
    unsigned int u;
    __builtin_memcpy(&u, &f, 4);
    unsigned int r = (u + 0x7FFFu + ((u >> 16) & 1u)) >> 16;
    return (unsigned short)r;
}
__device__ __forceinline__ float2 bpair(unsigned int u) {
    float2 r;
    unsigned int lo = u << 16;
    unsigned int hi = u & 0xFFFF0000u;
    __builtin_memcpy(&r.x, &lo, 4);
    __builtin_memcpy(&r.y, &hi, 4);
    return r;
}

typedef __attribute__((ext_vector_type(8))) short bf16x8;
typedef __attribute__((ext_vector_type(4))) float f32x4;

// ---------------- weight transpose + fp32->bf16 convert (once per call) ----------------
// in: R x C (row-major fp32), out: C x R bf16. grid (C/32, R/32, L), block (32,8)
__global__ void transcvt_k(const float* __restrict__ in,
                           unsigned short* __restrict__ out, int R, int C) {
    __shared__ float tile[32][33];
    const size_t zoff = (size_t)blockIdx.z * R * C;
    in += zoff; out += zoff;
    const int c0 = blockIdx.x * 32, r0 = blockIdx.y * 32;
    const int tx = threadIdx.x, ty = threadIdx.y;
#pragma unroll
    for (int i = 0; i < 32; i += 8)
        tile[ty + i][tx] = in[(size_t)(r0 + ty + i) * C + c0 + tx];
    __syncthreads();
#pragma unroll
    for (int i = 0; i < 32; i += 8)
        out[(size_t)(c0 + ty + i) * R + r0 + tx] = f2b(tile[tx][ty + i]);
}

// ---------------- GEMM: C[M,N] = A[M,K] @ Wt[N,K]^T + bias (+gelu) ----------------
// A is fp32 (AF32=1) or bf16 (AF32=0); Wt bf16; bias fp32; C bf16.
// 64x64 tile, 4 waves (2x2 of 32x32), mfma_f32_16x16x32_bf16, BK=32
template <int AF32>
__global__ __launch_bounds__(256) void gemm_bias_kernel(
    const void* __restrict__ Ap, const unsigned short* __restrict__ Wt,
    const float* __restrict__ bias, unsigned short* __restrict__ C,
    int M, int N, int K, int do_gelu) {
    __shared__ unsigned short As[64 * 40];
    __shared__ unsigned short Bs[64 * 40];
    const int tid = threadIdx.x;
    const int lane = tid & 63, wid = tid >> 6;
    const int m0 = blockIdx.y * 64, n0 = blockIdx.x * 64;
    const int wm = (wid >> 1) * 32, wn = (wid & 1) * 32;
    const int quad = lane >> 4, mrow = lane & 15;
    f32x4 acc[2][2] = {};
    const int arow = tid >> 2, ak = (tid & 3) << 3;
    const unsigned short* Bg = Wt + (size_t)(n0 + arow) * K + ak;
    const float* Agf = (const float*)Ap + (size_t)(m0 + arow) * K + ak;
    const unsigned short* Agb = (const unsigned short*)Ap + (size_t)(m0 + arow) * K + ak;

    typedef __attribute__((ext_vector_type(8))) short short8;
    for (int kb = 0; kb < K; kb += 32) {
        if (AF32) {
            float4 f0 = *(const float4*)(Agf + kb);
            float4 f1 = *(const float4*)(Agf + kb + 4);
            short8 t;
            t[0] = (short)f2b(f0.x); t[1] = (short)f2b(f0.y);
            t[2] = (short)f2b(f0.z); t[3] = (short)f2b(f0.w);
            t[4] = (short)f2b(f1.x); t[5] = (short)f2b(f1.y);
            t[6] = (short)f2b(f1.z); t[7] = (short)f2b(f1.w);
            *(short8*)&As[arow * 40 + ak] = t;
        } else {
            *(uint4*)&As[arow * 40 + ak] = *(const uint4*)(Agb + kb);
        }
        *(uint4*)&Bs[arow * 40 + ak] = *(const uint4*)(Bg + kb);
        __syncthreads();
        bf16x8 a0 = *(const bf16x8*)&As[(wm + mrow) * 40 + quad * 8];
        bf16x8 a1 = *(const bf16x8*)&As[(wm + 16 + mrow) * 40 + quad * 8];
        bf16x8 b0 = *(const bf16x8*)&Bs[(wn + mrow) * 40 + quad * 8];
        bf16x8 b1 = *(const bf16x8*)&Bs[(wn + 16 + mrow) * 40 + quad * 8];
        acc[0][0] = __builtin_amdgcn_mfma_f32_16x16x32_bf16(a0, b0, acc[0][0], 0, 0, 0);
        acc[0][1] = __builtin_amdgcn_mfma_f32_16x16x32_bf16(a0, b1, acc[0][1], 0, 0, 0);
        acc[1][0] = __builtin_amdgcn_mfma_f32_16x16x32_bf16(a1, b0, acc[1][0], 0, 0, 0);
        acc[1][1] = __builtin_amdgcn_mfma_f32_16x16x32_bf16(a1, b1, acc[1][1], 0, 0, 0);
        __syncthreads();
    }
#pragma unroll
    for (int i = 0; i < 2; i++)
#pragma unroll
        for (int j = 0; j < 2; j++) {
            const int col = n0 + wn + j * 16 + mrow;
            const float bv = bias[col];
#pragma unroll
            for (int r = 0; r < 4; r++) {
                const int row = m0 + wm + i * 16 + quad * 4 + r;
                float v = acc[i][j][r] + bv;
                if (do_gelu) v = 0.5f * v * (1.0f + erff(v * 0.70710678118654752f));
                C[(size_t)row * N + col] = f2b(v);
            }
        }
}

// ---------------- attention: flash-style, fp32 VALU ----------------
// grid: B*H*(S/8) = 16384 blocks, 512 threads (8 waves, one q-row per wave)
__global__ __launch_bounds__(512) void attn_kernel(
    const unsigned short* __restrict__ Qb, const unsigned short* __restrict__ Kb,
    const unsigned short* __restrict__ Vb, const float* __restrict__ sphp,
    unsigned short* __restrict__ Ctx) {
    __shared__ float Ks[64 * 36];
    __shared__ float Vs[64 * 36];
    __shared__ float Ss[8 * 64];
    const int tid = threadIdx.x, lane = tid & 63, wid = tid >> 6;
    const int bid = blockIdx.x;
    const int b = bid >> 11;          // / (8*256)
    const int h = (bid >> 8) & 7;
    const int qb = bid & 255;
    const int q = qb * 8 + wid;

    const unsigned short* qp = Qb + ((size_t)(b * 2048 + q) * 256 + h * 32);
    float qf[32];
#pragma unroll
    for (int i = 0; i < 4; i++) {
        uint4 u = *(const uint4*)(qp + i * 8);
        float2 p;
        p = bpair(u.x); qf[i * 8 + 0] = p.x; qf[i * 8 + 1] = p.y;
        p = bpair(u.y); qf[i * 8 + 2] = p.x; qf[i * 8 + 3] = p.y;
        p = bpair(u.z); qf[i * 8 + 4] = p.x; qf[i * 8 + 5] = p.y;
        p = bpair(u.w); qf[i * 8 + 6] = p.x; qf[i * 8 + 7] = p.y;
    }

    float m = -__builtin_inff(), l = 0.f;
    float acc[32];
#pragma unroll
    for (int d = 0; d < 32; ++d) acc[d] = 0.f;

    const int krow = tid >> 3, kg = tid & 7;
    const unsigned short* kp = Kb + ((size_t)(b * 2048 + krow) * 256 + h * 32 + kg * 4);
    const unsigned short* vp = Vb + ((size_t)(b * 2048 + krow) * 256 + h * 32 + kg * 4);
    const float* sp = sphp + ((size_t)(b * 2048 + q) * 2048 + lane);

    for (int kt = 0; kt < 32; ++kt) {
        {   // stage K,V (64 keys x 32 dims, fp32) + sph (8 q x 64 k)
            uint2 ku = *(const uint2*)(kp + (size_t)kt * 64 * 256);
            float2 a = bpair(ku.x), c = bpair(ku.y);
            float4 kv = {a.x, a.y, c.x, c.y};
            *(float4*)&Ks[krow * 36 + kg * 4] = kv;
            uint2 vu = *(const uint2*)(vp + (size_t)kt * 64 * 256);
            a = bpair(vu.x); c = bpair(vu.y);
            float4 vv = {a.x, a.y, c.x, c.y};
            *(float4*)&Vs[krow * 36 + kg * 4] = vv;
            Ss[wid * 64 + lane] = sp[kt * 64];
        }
        __syncthreads();

        float s = 0.f;
#pragma unroll
        for (int d4 = 0; d4 < 8; ++d4) {
            float4 kv = *(const float4*)&Ks[lane * 36 + d4 * 4];
            s += qf[d4 * 4 + 0] * kv.x + qf[d4 * 4 + 1] * kv.y +
                 qf[d4 * 4 + 2] * kv.z + qf[d4 * 4 + 3] * kv.w;
        }
        s = s * 0.17677669529663687f + Ss[wid * 64 + lane];

        float mx = s;
#pragma unroll
        for (int off = 32; off; off >>= 1) mx = fmaxf(mx, __shfl_xor(mx, off));
        const float mn = fmaxf(m, mx);
        const float al = __expf(m - mn);
        const float p = __expf(s - mn);
        l = l * al + p;
#pragma unroll
        for (int d4 = 0; d4 < 8; ++d4) {
            float4 vv = *(const float4*)&Vs[lane * 36 + d4 * 4];
            acc[d4 * 4 + 0] = acc[d4 * 4 + 0] * al + p * vv.x;
            acc[d4 * 4 + 1] = acc[d4 * 4 + 1] * al + p * vv.y;
            acc[d4 * 4 + 2] = acc[d4 * 4 + 2] * al + p * vv.z;
            acc[d4 * 4 + 3] = acc[d4 * 4 + 3] * al + p * vv.w;
        }
        m = mn;
        __syncthreads();
    }

#pragma unroll
    for (int off = 32; off; off >>= 1) l += __shfl_xor(l, off);
    float ov = 0.f;
#pragma unroll
    for (int d = 0; d < 32; ++d) {
        float t = acc[d];
#pragma unroll
        for (int off = 32; off; off >>= 1) t += __shfl_xor(t, off);
        if (lane == d) ov = t;
    }
    if (lane < 32)
        Ctx[(size_t)(b * 2048 + q) * 256 + h * 32 + lane] = f2b(ov / l);
}

// ---------------- fused residual + LayerNorm (fp32 stream) ----------------
// one wave per row of 256; grid = rows/4, block 256
__global__ __launch_bounds__(256) void add_ln_kernel(
    const float* __restrict__ x, const unsigned short* __restrict__ r,
    const float* __restrict__ g, const float* __restrict__ be,
    float* __restrict__ out) {
    const int lane = threadIdx.x & 63, wid = threadIdx.x >> 6;
    const size_t row = (size_t)blockIdx.x * 4 + wid;
    float4 xv = *(const float4*)(x + row * 256 + lane * 4);
    uint2 ru = *(const uint2*)(r + row * 256 + lane * 4);
    float2 ra = bpair(ru.x), rb = bpair(ru.y);
    float v[4] = {xv.x + ra.x, xv.y + ra.y, xv.z + rb.x, xv.w + rb.y};
    float sum = v[0] + v[1] + v[2] + v[3];
#pragma unroll
    for (int off = 32; off; off >>= 1) sum += __shfl_xor(sum, off);
    const float mu = sum * (1.f / 256.f);
    float sq = 0.f;
#pragma unroll
    for (int i = 0; i < 4; i++) { float d = v[i] - mu; sq += d * d; }
#pragma unroll
    for (int off = 32; off; off >>= 1) sq += __shfl_xor(sq, off);
    const float rs = rsqrtf(sq * (1.f / 256.f) + 1e-5f);
    float4 o;
    o.x = (v[0] - mu) * rs * g[lane * 4 + 0] + be[lane * 4 + 0];
    o.y = (v[1] - mu) * rs * g[lane * 4 + 1] + be[lane * 4 + 1];
    o.z = (v[2] - mu) * rs * g[lane * 4 + 2] + be[lane * 4 + 2];
    o.w = (v[3] - mu) * rs * g[lane * 4 + 3] + be[lane * 4 + 3];
    *(float4*)(out + row * 256 + lane * 4) = o;
}

// ---------------- launch ----------------
extern "C" void kernel_launch(void* const* d_in, const int* in_sizes, int n_in,
                              void* d_out, int out_size, void* d_ws, size_t ws_size,
                              hipStream_t stream) {
    const float* src = (const float*)d_in[0];
    const float* sph = (const float*)d_in[1];
    const float* Wq  = (const float*)d_in[2];
    const float* bq  = (const float*)d_in[3];
    const float* Wk  = (const float*)d_in[4];
    const float* bk  = (const float*)d_in[5];
    const float* Wv  = (const float*)d_in[6];
    const float* bv  = (const float*)d_in[7];
    const float* Wo  = (const float*)d_in[8];
    const float* bo  = (const float*)d_in[9];
    const float* W1  = (const float*)d_in[10];
    const float* b1  = (const float*)d_in[11];
    const float* W2  = (const float*)d_in[12];
    const float* b2  = (const float*)d_in[13];
    const float* g1  = (const float*)d_in[14];
    const float* be1 = (const float*)d_in[15];
    const float* g2  = (const float*)d_in[16];
    const float* be2 = (const float*)d_in[17];

    char* ws = (char*)d_ws;
    float* X = (float*)d_out;                               // fp32 activations in d_out
    unsigned short* Q   = (unsigned short*)(ws + 0);
    unsigned short* Kb  = (unsigned short*)(ws + 8388608);
    unsigned short* V   = (unsigned short*)(ws + 16777216);
    unsigned short* CTX = (unsigned short*)(ws + 25165824);
    unsigned short* T2  = (unsigned short*)(ws + 33554432);
    unsigned short* H   = Q;                                // 16384x1024 bf16 reuses Q..CTX
    unsigned short* WtQ = (unsigned short*)(ws + 41943040);
    unsigned short* WtK = (unsigned short*)(ws + 42598400);
    unsigned short* WtV = (unsigned short*)(ws + 43253760);
    unsigned short* WtO = (unsigned short*)(ws + 43909120);
    unsigned short* Wt1 = (unsigned short*)(ws + 44564480);
    unsigned short* Wt2 = (unsigned short*)(ws + 47185920);

    const dim3 tb(32, 8);
    transcvt_k<<<dim3(8, 8, 5), tb, 0, stream>>>(Wq, WtQ, 256, 256);
    transcvt_k<<<dim3(8, 8, 5), tb, 0, stream>>>(Wk, WtK, 256, 256);
    transcvt_k<<<dim3(8, 8, 5), tb, 0, stream>>>(Wv, WtV, 256, 256);
    transcvt_k<<<dim3(8, 8, 5), tb, 0, stream>>>(Wo, WtO, 256, 256);
    transcvt_k<<<dim3(32, 8, 5), tb, 0, stream>>>(W1, Wt1, 256, 1024);
    transcvt_k<<<dim3(8, 32, 5), tb, 0, stream>>>(W2, Wt2, 1024, 256);

    hipMemcpyAsync(X, src, 16777216, hipMemcpyDeviceToDevice, stream);

    const int M = 16384;
    for (int lyr = 0; lyr < 5; ++lyr) {
        gemm_bias_kernel<1><<<dim3(4, 256), 256, 0, stream>>>(
            X, WtQ + lyr * 65536, bq + lyr * 256, Q, M, 256, 256, 0);
        gemm_bias_kernel<1><<<dim3(4, 256), 256, 0, stream>>>(
            X, WtK + lyr * 65536, bk + lyr * 256, Kb, M, 256, 256, 0);
        gemm_bias_kernel<1><<<dim3(4, 256), 256, 0, stream>>>(
            X, WtV + lyr * 65536, bv + lyr * 256, V, M, 256, 256, 0);
        attn_kernel<<<16384, 512, 0, stream>>>(Q, Kb, V, sph, CTX);
        gemm_bias_kernel<0><<<dim3(4, 256), 256, 0, stream>>>(
            CTX, WtO + lyr * 65536, bo + lyr * 256, T2, M, 256, 256, 0);
        add_ln_kernel<<<4096, 256, 0, stream>>>(X, T2, g1 + lyr * 256, be1 + lyr * 256, X);
        gemm_bias_kernel<1><<<dim3(16, 256), 256, 0, stream>>>(
            X, Wt1 + lyr * 262144, b1 + lyr * 1024, H, M, 1024, 256, 1);
        gemm_bias_kernel<0><<<dim3(4, 256), 256, 0, stream>>>(
            H, Wt2 + lyr * 262144, b2 + lyr * 256, T2, M, 256, 1024, 0);
        add_ln_kernel<<<4096, 256, 0, stream>>>(X, T2, g2 + lyr * 256, be2 + lyr * 256, X);
    }
}

// Round 4
// 1958.645 us; speedup vs baseline: 6.5658x; 6.5658x over previous
//
#include <hip/hip_runtime.h>
#include <cstdint>

// ---------------- bf16 helpers ----------------
__device__ __forceinline__ float b2f(unsigned short u) {
    unsigned int t = ((unsigned int)u) << 16;
    float f;
    __builtin_memcpy(&f, &t, 4);
    return f;
}
__device__ __forceinline__ unsigned short f2b(float f) {
    unsigned int u;
    __builtin_memcpy(&u, &f, 4);
    unsigned int r = (u + 0x7FFFu + ((u >> 16) & 1u)) >> 16;
    return (unsigned short)r;
}
__device__ __forceinline__ float2 bpair(unsigned int u) {
    float2 r;
    unsigned int lo = u << 16;
    unsigned int hi = u & 0xFFFF0000u;
    __builtin_memcpy(&r.x, &lo, 4);
    __builtin_memcpy(&r.y, &hi, 4);
    return r;
}

typedef __attribute__((ext_vector_type(8))) short bf16x8;
typedef __attribute__((ext_vector_type(4))) float f32x4;

// ---------------- weight transpose + fp32->bf16 convert (once per call) ----------------
__global__ void transcvt_k(const float* __restrict__ in,
                           unsigned short* __restrict__ out, int R, int C) {
    __shared__ float tile[32][33];
    const size_t zoff = (size_t)blockIdx.z * R * C;
    in += zoff; out += zoff;
    const int c0 = blockIdx.x * 32, r0 = blockIdx.y * 32;
    const int tx = threadIdx.x, ty = threadIdx.y;
#pragma unroll
    for (int i = 0; i < 32; i += 8)
        tile[ty + i][tx] = in[(size_t)(r0 + ty + i) * C + c0 + tx];
    __syncthreads();
#pragma unroll
    for (int i = 0; i < 32; i += 8)
        out[(size_t)(c0 + ty + i) * R + r0 + tx] = f2b(tile[tx][ty + i]);
}

// ---------------- GEMM: C[M,N] = A[M,K] @ Wt[N,K]^T + bias (+gelu) ----------------
template <int AF32>
__global__ __launch_bounds__(256) void gemm_bias_kernel(
    const void* __restrict__ Ap, const unsigned short* __restrict__ Wt,
    const float* __restrict__ bias, unsigned short* __restrict__ C,
    int M, int N, int K, int do_gelu) {
    __shared__ unsigned short As[64 * 40];
    __shared__ unsigned short Bs[64 * 40];
    const int tid = threadIdx.x;
    const int lane = tid & 63, wid = tid >> 6;
    const int m0 = blockIdx.y * 64, n0 = blockIdx.x * 64;
    const int wm = (wid >> 1) * 32, wn = (wid & 1) * 32;
    const int quad = lane >> 4, mrow = lane & 15;
    f32x4 acc[2][2] = {};
    const int arow = tid >> 2, ak = (tid & 3) << 3;
    const unsigned short* Bg = Wt + (size_t)(n0 + arow) * K + ak;
    const float* Agf = (const float*)Ap + (size_t)(m0 + arow) * K + ak;
    const unsigned short* Agb = (const unsigned short*)Ap + (size_t)(m0 + arow) * K + ak;

    typedef __attribute__((ext_vector_type(8))) short short8;
    for (int kb = 0; kb < K; kb += 32) {
        if (AF32) {
            float4 f0 = *(const float4*)(Agf + kb);
            float4 f1 = *(const float4*)(Agf + kb + 4);
            short8 t;
            t[0] = (short)f2b(f0.x); t[1] = (short)f2b(f0.y);
            t[2] = (short)f2b(f0.z); t[3] = (short)f2b(f0.w);
            t[4] = (short)f2b(f1.x); t[5] = (short)f2b(f1.y);
            t[6] = (short)f2b(f1.z); t[7] = (short)f2b(f1.w);
            *(short8*)&As[arow * 40 + ak] = t;
        } else {
            *(uint4*)&As[arow * 40 + ak] = *(const uint4*)(Agb + kb);
        }
        *(uint4*)&Bs[arow * 40 + ak] = *(const uint4*)(Bg + kb);
        __syncthreads();
        bf16x8 a0 = *(const bf16x8*)&As[(wm + mrow) * 40 + quad * 8];
        bf16x8 a1 = *(const bf16x8*)&As[(wm + 16 + mrow) * 40 + quad * 8];
        bf16x8 b0 = *(const bf16x8*)&Bs[(wn + mrow) * 40 + quad * 8];
        bf16x8 b1 = *(const bf16x8*)&Bs[(wn + 16 + mrow) * 40 + quad * 8];
        acc[0][0] = __builtin_amdgcn_mfma_f32_16x16x32_bf16(a0, b0, acc[0][0], 0, 0, 0);
        acc[0][1] = __builtin_amdgcn_mfma_f32_16x16x32_bf16(a0, b1, acc[0][1], 0, 0, 0);
        acc[1][0] = __builtin_amdgcn_mfma_f32_16x16x32_bf16(a1, b0, acc[1][0], 0, 0, 0);
        acc[1][1] = __builtin_amdgcn_mfma_f32_16x16x32_bf16(a1, b1, acc[1][1], 0, 0, 0);
        __syncthreads();
    }
#pragma unroll
    for (int i = 0; i < 2; i++)
#pragma unroll
        for (int j = 0; j < 2; j++) {
            const int col = n0 + wn + j * 16 + mrow;
            const float bv = bias[col];
#pragma unroll
            for (int r = 0; r < 4; r++) {
                const int row = m0 + wm + i * 16 + quad * 4 + r;
                float v = acc[i][j][r] + bv;
                if (do_gelu) v = 0.5f * v * (1.0f + erff(v * 0.70710678118654752f));
                C[(size_t)row * N + col] = f2b(v);
            }
        }
}

// ---------------- attention: flash-style, MFMA ----------------
// grid: B*H*(S/64) = 2048 blocks, 256 threads (4 waves, 16 q-rows per wave).
// Ks: [64 keys][32 dims] stride 40. Vt: [32 dims][64 keys] stride 72.
// Ps: per-wave [16 qrows][64 keys] stride 72. (strides: >= extent, multiple of
// 8 elems for 16B-aligned bf16x8 reads; 40/72 give only 2-way bank aliasing.)
__global__ __launch_bounds__(256) void attn_mfma(
    const unsigned short* __restrict__ Qb, const unsigned short* __restrict__ Kb,
    const unsigned short* __restrict__ Vb, const float* __restrict__ sph,
    unsigned short* __restrict__ Ctx) {
    __shared__ unsigned short Ks[64 * 40];
    __shared__ unsigned short Vt[32 * 72];
    __shared__ unsigned short Ps[4][16 * 72];

    const int tid = threadIdx.x, lane = tid & 63, wid = tid >> 6;
    const int quad = lane >> 4, lq = lane & 15;
    const int bid = blockIdx.x;
    const int h = bid & 7, qt = (bid >> 3) & 31, b = bid >> 8;
    const int q0 = qt * 64;
    const size_t bS = (size_t)b * 2048;

    // staging addresses
    const int skey = tid >> 2, sdg = (tid & 3) << 3;
    const unsigned short* kgp = Kb + (bS + skey) * 256 + h * 32 + sdg;
    const int vkp = tid & 31, vdg = (tid >> 5) << 2;
    const unsigned short* vgp = Vb + (bS + 2 * vkp) * 256 + h * 32 + vdg;

    // Q fragment (A-layout: row = lq, k = quad*8+j), persistent
    const bf16x8 qf = *(const bf16x8*)(Qb + (bS + q0 + wid * 16 + lq) * 256 + h * 32 + quad * 8);

    // sph bias: rows q0+wid*16+quad*4+r, cols k0+lq+16j
    const float* sp = sph + ((size_t)b * 2048 + q0 + wid * 16 + quad * 4) * 2048 + lq;

    float m_r[4] = {-__builtin_inff(), -__builtin_inff(), -__builtin_inff(), -__builtin_inff()};
    float l_r[4] = {0.f, 0.f, 0.f, 0.f};
    f32x4 o0 = {}, o1 = {};
    const float SCALE = 0.17677669529663687f;   // 1/sqrt(32)

    for (int kt = 0; kt < 32; ++kt) {
        const int k0 = kt * 64;
        __syncthreads();                        // protect Ks/Vt reuse
        // stage K tile (coalesced 16B)
        *(uint4*)&Ks[skey * 40 + sdg] = *(const uint4*)(kgp + (size_t)k0 * 256);
        // stage V transposed: pack 2 keys per u32
        {
            uint2 va = *(const uint2*)(vgp + (size_t)k0 * 256);
            uint2 vb2 = *(const uint2*)(vgp + (size_t)k0 * 256 + 256);
            *(unsigned int*)&Vt[(vdg + 0) * 72 + 2 * vkp] = (va.x & 0xFFFFu) | (vb2.x << 16);
            *(unsigned int*)&Vt[(vdg + 1) * 72 + 2 * vkp] = (va.x >> 16) | (vb2.x & 0xFFFF0000u);
            *(unsigned int*)&Vt[(vdg + 2) * 72 + 2 * vkp] = (va.y & 0xFFFFu) | (vb2.y << 16);
            *(unsigned int*)&Vt[(vdg + 3) * 72 + 2 * vkp] = (va.y >> 16) | (vb2.y & 0xFFFF0000u);
        }
        __syncthreads();

        // S = Q K^T : one MFMA per 16-key group
        const f32x4 zf = {};
        f32x4 sa0 = __builtin_amdgcn_mfma_f32_16x16x32_bf16(
            qf, *(const bf16x8*)&Ks[(0  + lq) * 40 + quad * 8], zf, 0, 0, 0);
        f32x4 sa1 = __builtin_amdgcn_mfma_f32_16x16x32_bf16(
            qf, *(const bf16x8*)&Ks[(16 + lq) * 40 + quad * 8], zf, 0, 0, 0);
        f32x4 sa2 = __builtin_amdgcn_mfma_f32_16x16x32_bf16(
            qf, *(const bf16x8*)&Ks[(32 + lq) * 40 + quad * 8], zf, 0, 0, 0);
        f32x4 sa3 = __builtin_amdgcn_mfma_f32_16x16x32_bf16(
            qf, *(const bf16x8*)&Ks[(48 + lq) * 40 + quad * 8], zf, 0, 0, 0);

        // bias + online softmax (per C-layout row = quad*4+r)
#pragma unroll
        for (int r = 0; r < 4; ++r) {
            const float* spr = sp + (size_t)r * 2048 + k0;
            float s0 = sa0[r] * SCALE + spr[0];
            float s1 = sa1[r] * SCALE + spr[16];
            float s2 = sa2[r] * SCALE + spr[32];
            float s3 = sa3[r] * SCALE + spr[48];
            float t = fmaxf(fmaxf(s0, s1), fmaxf(s2, s3));
            t = fmaxf(t, __shfl_xor(t, 1));
            t = fmaxf(t, __shfl_xor(t, 2));
            t = fmaxf(t, __shfl_xor(t, 4));
            t = fmaxf(t, __shfl_xor(t, 8));
            const float mn = fmaxf(m_r[r], t);
            const float al = __expf(m_r[r] - mn);
            m_r[r] = mn;
            const float p0 = __expf(s0 - mn), p1 = __expf(s1 - mn);
            const float p2 = __expf(s2 - mn), p3 = __expf(s3 - mn);
            float rs = (p0 + p1) + (p2 + p3);
            rs += __shfl_xor(rs, 1);
            rs += __shfl_xor(rs, 2);
            rs += __shfl_xor(rs, 4);
            rs += __shfl_xor(rs, 8);
            l_r[r] = l_r[r] * al + rs;
            o0[r] *= al; o1[r] *= al;
            unsigned short* pw = &Ps[wid][(quad * 4 + r) * 72 + lq];
            pw[0]  = f2b(p0);
            pw[16] = f2b(p1);
            pw[32] = f2b(p2);
            pw[48] = f2b(p3);
        }

        // PV: P from wave-private LDS slab (in-wave dependency only), V^T as B
#pragma unroll
        for (int k2 = 0; k2 < 2; ++k2) {
            bf16x8 pf = *(const bf16x8*)&Ps[wid][lq * 72 + k2 * 32 + quad * 8];
            o0 = __builtin_amdgcn_mfma_f32_16x16x32_bf16(
                pf, *(const bf16x8*)&Vt[(0  + lq) * 72 + k2 * 32 + quad * 8], o0, 0, 0, 0);
            o1 = __builtin_amdgcn_mfma_f32_16x16x32_bf16(
                pf, *(const bf16x8*)&Vt[(16 + lq) * 72 + k2 * 32 + quad * 8], o1, 0, 0, 0);
        }
    }

    // epilogue: O / l, C-layout scatter (2B stores, 16-lane contiguous)
    unsigned short* op = Ctx + (bS + q0 + wid * 16 + quad * 4) * 256 + h * 32;
#pragma unroll
    for (int r = 0; r < 4; ++r) {
        const float inv = 1.f / l_r[r];
        op[r * 256 + lq]      = f2b(o0[r] * inv);
        op[r * 256 + 16 + lq] = f2b(o1[r] * inv);
    }
}

// ---------------- fused residual + LayerNorm (fp32 stream) ----------------
__global__ __launch_bounds__(256) void add_ln_kernel(
    const float* __restrict__ x, const unsigned short* __restrict__ r,
    const float* __restrict__ g, const float* __restrict__ be,
    float* __restrict__ out) {
    const int lane = threadIdx.x & 63, wid = threadIdx.x >> 6;
    const size_t row = (size_t)blockIdx.x * 4 + wid;
    float4 xv = *(const float4*)(x + row * 256 + lane * 4);
    uint2 ru = *(const uint2*)(r + row * 256 + lane * 4);
    float2 ra = bpair(ru.x), rb = bpair(ru.y);
    float v[4] = {xv.x + ra.x, xv.y + ra.y, xv.z + rb.x, xv.w + rb.y};
    float sum = v[0] + v[1] + v[2] + v[3];
#pragma unroll
    for (int off = 32; off; off >>= 1) sum += __shfl_xor(sum, off);
    const float mu = sum * (1.f / 256.f);
    float sq = 0.f;
#pragma unroll
    for (int i = 0; i < 4; i++) { float d = v[i] - mu; sq += d * d; }
#pragma unroll
    for (int off = 32; off; off >>= 1) sq += __shfl_xor(sq, off);
    const float rs = rsqrtf(sq * (1.f / 256.f) + 1e-5f);
    float4 o;
    o.x = (v[0] - mu) * rs * g[lane * 4 + 0] + be[lane * 4 + 0];
    o.y = (v[1] - mu) * rs * g[lane * 4 + 1] + be[lane * 4 + 1];
    o.z = (v[2] - mu) * rs * g[lane * 4 + 2] + be[lane * 4 + 2];
    o.w = (v[3] - mu) * rs * g[lane * 4 + 3] + be[lane * 4 + 3];
    *(float4*)(out + row * 256 + lane * 4) = o;
}

// ---------------- launch ----------------
extern "C" void kernel_launch(void* const* d_in, const int* in_sizes, int n_in,
                              void* d_out, int out_size, void* d_ws, size_t ws_size,
                              hipStream_t stream) {
    const float* src = (const float*)d_in[0];
    const float* sph = (const float*)d_in[1];
    const float* Wq  = (const float*)d_in[2];
    const float* bq  = (const float*)d_in[3];
    const float* Wk  = (const float*)d_in[4];
    const float* bk  = (const float*)d_in[5];
    const float* Wv  = (const float*)d_in[6];
    const float* bv  = (const float*)d_in[7];
    const float* Wo  = (const float*)d_in[8];
    const float* bo  = (const float*)d_in[9];
    const float* W1  = (const float*)d_in[10];
    const float* b1  = (const float*)d_in[11];
    const float* W2  = (const float*)d_in[12];
    const float* b2  = (const float*)d_in[13];
    const float* g1  = (const float*)d_in[14];
    const float* be1 = (const float*)d_in[15];
    const float* g2  = (const float*)d_in[16];
    const float* be2 = (const float*)d_in[17];

    char* ws = (char*)d_ws;
    float* X = (float*)d_out;                               // fp32 activations in d_out
    unsigned short* Q   = (unsigned short*)(ws + 0);
    unsigned short* Kb  = (unsigned short*)(ws + 8388608);
    unsigned short* V   = (unsigned short*)(ws + 16777216);
    unsigned short* CTX = (unsigned short*)(ws + 25165824);
    unsigned short* T2  = (unsigned short*)(ws + 33554432);
    unsigned short* H   = Q;                                // 16384x1024 bf16 reuses Q..CTX
    unsigned short* WtQ = (unsigned short*)(ws + 41943040);
    unsigned short* WtK = (unsigned short*)(ws + 42598400);
    unsigned short* WtV = (unsigned short*)(ws + 43253760);
    unsigned short* WtO = (unsigned short*)(ws + 43909120);
    unsigned short* Wt1 = (unsigned short*)(ws + 44564480);
    unsigned short* Wt2 = (unsigned short*)(ws + 47185920);

    const dim3 tb(32, 8);
    transcvt_k<<<dim3(8, 8, 5), tb, 0, stream>>>(Wq, WtQ, 256, 256);
    transcvt_k<<<dim3(8, 8, 5), tb, 0, stream>>>(Wk, WtK, 256, 256);
    transcvt_k<<<dim3(8, 8, 5), tb, 0, stream>>>(Wv, WtV, 256, 256);
    transcvt_k<<<dim3(8, 8, 5), tb, 0, stream>>>(Wo, WtO, 256, 256);
    transcvt_k<<<dim3(32, 8, 5), tb, 0, stream>>>(W1, Wt1, 256, 1024);
    transcvt_k<<<dim3(8, 32, 5), tb, 0, stream>>>(W2, Wt2, 1024, 256);

    hipMemcpyAsync(X, src, 16777216, hipMemcpyDeviceToDevice, stream);

    const int M = 16384;
    for (int lyr = 0; lyr < 5; ++lyr) {
        gemm_bias_kernel<1><<<dim3(4, 256), 256, 0, stream>>>(
            X, WtQ + lyr * 65536, bq + lyr * 256, Q, M, 256, 256, 0);
        gemm_bias_kernel<1><<<dim3(4, 256), 256, 0, stream>>>(
            X, WtK + lyr * 65536, bk + lyr * 256, Kb, M, 256, 256, 0);
        gemm_bias_kernel<1><<<dim3(4, 256), 256, 0, stream>>>(
            X, WtV + lyr * 65536, bv + lyr * 256, V, M, 256, 256, 0);
        attn_mfma<<<2048, 256, 0, stream>>>(Q, Kb, V, sph, CTX);
        gemm_bias_kernel<0><<<dim3(4, 256), 256, 0, stream>>>(
            CTX, WtO + lyr * 65536, bo + lyr * 256, T2, M, 256, 256, 0);
        add_ln_kernel<<<4096, 256, 0, stream>>>(X, T2, g1 + lyr * 256, be1 + lyr * 256, X);
        gemm_bias_kernel<1><<<dim3(16, 256), 256, 0, stream>>>(
            X, Wt1 + lyr * 262144, b1 + lyr * 1024, H, M, 1024, 256, 1);
        gemm_bias_kernel<0><<<dim3(4, 256), 256, 0, stream>>>(
            H, Wt2 + lyr * 262144, b2 + lyr * 256, T2, M, 256, 1024, 0);
        add_ln_kernel<<<4096, 256, 0, stream>>>(X, T2, g2 + lyr * 256, be2 + lyr * 256, X);
    }
}

// Round 6
// 1567.529 us; speedup vs baseline: 8.2041x; 1.2495x over previous
//
#include <hip/hip_runtime.h>
#include <cstdint>

// ---------------- bf16 helpers ----------------
__device__ __forceinline__ float b2f(unsigned short u) {
    unsigned int t = ((unsigned int)u) << 16;
    float f;
    __builtin_memcpy(&f, &t, 4);
    return f;
}
__device__ __forceinline__ unsigned short f2b(float f) {
    unsigned int u;
    __builtin_memcpy(&u, &f, 4);
    unsigned int r = (u + 0x7FFFu + ((u >> 16) & 1u)) >> 16;
    return (unsigned short)r;
}
__device__ __forceinline__ float2 bpair(unsigned int u) {
    float2 r;
    unsigned int lo = u << 16;
    unsigned int hi = u & 0xFFFF0000u;
    __builtin_memcpy(&r.x, &lo, 4);
    __builtin_memcpy(&r.y, &hi, 4);
    return r;
}

typedef __attribute__((ext_vector_type(8))) short bf16x8;
typedef __attribute__((ext_vector_type(4))) float f32x4;

#define LOG2E 1.4426950408889634f
#define SC2   0.2550348595f   /* (1/sqrt(32)) * log2(e) */

// ---------------- weight transpose + fp32->bf16 convert (once per call) ----------------
// in: R x C (row-major fp32, layer stride in_z), out: C x R bf16 at layer stride out_z.
__global__ void transcvt_k(const float* __restrict__ in,
                           unsigned short* __restrict__ out, int R, int C,
                           int in_z, int out_z) {
    __shared__ float tile[32][33];
    in += (size_t)blockIdx.z * in_z;
    out += (size_t)blockIdx.z * out_z;
    const int c0 = blockIdx.x * 32, r0 = blockIdx.y * 32;
    const int tx = threadIdx.x, ty = threadIdx.y;
#pragma unroll
    for (int i = 0; i < 32; i += 8)
        tile[ty + i][tx] = in[(size_t)(r0 + ty + i) * C + c0 + tx];
    __syncthreads();
#pragma unroll
    for (int i = 0; i < 32; i += 8)
        out[(size_t)(c0 + ty + i) * R + r0 + tx] = f2b(tile[tx][ty + i]);
}

// ---------------- sph -> bf16 * log2e (once per call) ----------------
__global__ __launch_bounds__(256) void sph_cvt(const float* __restrict__ in,
                                               unsigned short* __restrict__ out) {
    const size_t idx = (size_t)blockIdx.x * 256 + threadIdx.x;
    const float4 a = ((const float4*)in)[idx * 2];
    const float4 b = ((const float4*)in)[idx * 2 + 1];
    uint4 o;
    o.x = (unsigned)f2b(a.x * LOG2E) | ((unsigned)f2b(a.y * LOG2E) << 16);
    o.y = (unsigned)f2b(a.z * LOG2E) | ((unsigned)f2b(a.w * LOG2E) << 16);
    o.z = (unsigned)f2b(b.x * LOG2E) | ((unsigned)f2b(b.y * LOG2E) << 16);
    o.w = (unsigned)f2b(b.z * LOG2E) | ((unsigned)f2b(b.w * LOG2E) << 16);
    ((uint4*)out)[idx] = o;
}

// ---------------- GEMM: C[M,N] = A[M,K] @ Wt[N,K]^T + bias (+gelu) ----------------
// QKVB: bias selected from 3 pointers by col>>8 (fused QKV, N=768).
template <int AF32, int QKVB>
__global__ __launch_bounds__(256) void gemm_bias_kernel(
    const void* __restrict__ Ap, const unsigned short* __restrict__ Wt,
    const float* __restrict__ biasQ, const float* __restrict__ biasK,
    const float* __restrict__ biasV, unsigned short* __restrict__ C,
    int M, int N, int K, int do_gelu) {
    __shared__ unsigned short As[64 * 40];
    __shared__ unsigned short Bs[64 * 40];
    const int tid = threadIdx.x;
    const int lane = tid & 63, wid = tid >> 6;
    const int m0 = blockIdx.y * 64, n0 = blockIdx.x * 64;
    const int wm = (wid >> 1) * 32, wn = (wid & 1) * 32;
    const int quad = lane >> 4, mrow = lane & 15;
    f32x4 acc[2][2] = {};
    const int arow = tid >> 2, ak = (tid & 3) << 3;
    const unsigned short* Bg = Wt + (size_t)(n0 + arow) * K + ak;
    const float* Agf = (const float*)Ap + (size_t)(m0 + arow) * K + ak;
    const unsigned short* Agb = (const unsigned short*)Ap + (size_t)(m0 + arow) * K + ak;

    typedef __attribute__((ext_vector_type(8))) short short8;
    for (int kb = 0; kb < K; kb += 32) {
        if (AF32) {
            float4 f0 = *(const float4*)(Agf + kb);
            float4 f1 = *(const float4*)(Agf + kb + 4);
            short8 t;
            t[0] = (short)f2b(f0.x); t[1] = (short)f2b(f0.y);
            t[2] = (short)f2b(f0.z); t[3] = (short)f2b(f0.w);
            t[4] = (short)f2b(f1.x); t[5] = (short)f2b(f1.y);
            t[6] = (short)f2b(f1.z); t[7] = (short)f2b(f1.w);
            *(short8*)&As[arow * 40 + ak] = t;
        } else {
            *(uint4*)&As[arow * 40 + ak] = *(const uint4*)(Agb + kb);
        }
        *(uint4*)&Bs[arow * 40 + ak] = *(const uint4*)(Bg + kb);
        __syncthreads();
        bf16x8 a0 = *(const bf16x8*)&As[(wm + mrow) * 40 + quad * 8];
        bf16x8 a1 = *(const bf16x8*)&As[(wm + 16 + mrow) * 40 + quad * 8];
        bf16x8 b0 = *(const bf16x8*)&Bs[(wn + mrow) * 40 + quad * 8];
        bf16x8 b1 = *(const bf16x8*)&Bs[(wn + 16 + mrow) * 40 + quad * 8];
        acc[0][0] = __builtin_amdgcn_mfma_f32_16x16x32_bf16(a0, b0, acc[0][0], 0, 0, 0);
        acc[0][1] = __builtin_amdgcn_mfma_f32_16x16x32_bf16(a0, b1, acc[0][1], 0, 0, 0);
        acc[1][0] = __builtin_amdgcn_mfma_f32_16x16x32_bf16(a1, b0, acc[1][0], 0, 0, 0);
        acc[1][1] = __builtin_amdgcn_mfma_f32_16x16x32_bf16(a1, b1, acc[1][1], 0, 0, 0);
        __syncthreads();
    }
    const float* bp;
    if (QKVB) {
        const int bsel = n0 >> 8;
        bp = bsel == 0 ? biasQ : (bsel == 1 ? biasK : biasV);
    } else {
        bp = biasQ;
    }
#pragma unroll
    for (int i = 0; i < 2; i++)
#pragma unroll
        for (int j = 0; j < 2; j++) {
            const int col = n0 + wn + j * 16 + mrow;
            const float bv = QKVB ? bp[col & 255] : bp[col];
#pragma unroll
            for (int r = 0; r < 4; r++) {
                const int row = m0 + wm + i * 16 + quad * 4 + r;
                float v = acc[i][j][r] + bv;
                if (do_gelu) v = 0.5f * v * (1.0f + erff(v * 0.70710678118654752f));
                C[(size_t)row * N + col] = f2b(v);
            }
        }
}

// ---------------- attention: flash-style MFMA, no-max exp2 softmax ----------------
// grid 2048 blocks: h = bid>>8 (high bits -> the 8 heads of one (b,qt) share an
// XCD and run concurrently -> sph L2 reuse). 4 waves, 16 q-rows each.
// QKV buffer row stride 768 (fused); Ctx stride 256.
// No online max: p = exp2(qk*SC2 + sph*log2e) directly (score range << fp32
// exponent range), l accumulated per-lane, reduced once at the end.
template <int SPHB16>
__global__ __launch_bounds__(256) void attn_mfma(
    const unsigned short* __restrict__ Qb, const unsigned short* __restrict__ Kb,
    const unsigned short* __restrict__ Vb, const float* __restrict__ sphf,
    const unsigned short* __restrict__ sphb, unsigned short* __restrict__ Ctx) {
    __shared__ unsigned short Ks[64 * 40];
    __shared__ unsigned short Vt[32 * 72];
    __shared__ unsigned short Ps[4][16 * 72];

    const int tid = threadIdx.x, lane = tid & 63, wid = tid >> 6;
    const int quad = lane >> 4, lq = lane & 15;
    const int bid = blockIdx.x;
    const int h = bid >> 8, b = (bid >> 5) & 7, qt = bid & 31;
    const int q0 = qt * 64;
    const size_t bS = (size_t)b * 2048;

    // staging addresses (QKV stride 768)
    const int skey = tid >> 2, sdg = (tid & 3) << 3;
    const unsigned short* kgp = Kb + (bS + skey) * 768 + h * 32 + sdg;
    const int vkp = tid & 31, vdg = (tid >> 5) << 2;
    const unsigned short* vgp = Vb + (bS + 2 * vkp) * 768 + h * 32 + vdg;

    // Q fragment (A-layout: row = lq, k = quad*8+j), persistent
    const bf16x8 qf = *(const bf16x8*)(Qb + (bS + q0 + wid * 16 + lq) * 768 + h * 32 + quad * 8);

    // sph bias: rows q0+wid*16+quad*4+r, cols k0+lq+16j
    const size_t sprow = ((size_t)b * 2048 + q0 + wid * 16 + quad * 4) * 2048 + lq;
    const float* spf = sphf + sprow;
    const unsigned short* spb = sphb + sprow;

    float l_r[4] = {0.f, 0.f, 0.f, 0.f};
    f32x4 o0 = {}, o1 = {};

    for (int kt = 0; kt < 32; ++kt) {
        const int k0 = kt * 64;
        __syncthreads();                        // protect Ks/Vt reuse
        *(uint4*)&Ks[skey * 40 + sdg] = *(const uint4*)(kgp + (size_t)k0 * 768);
        {
            uint2 va = *(const uint2*)(vgp + (size_t)k0 * 768);
            uint2 vb2 = *(const uint2*)(vgp + (size_t)k0 * 768 + 768);
            *(unsigned int*)&Vt[(vdg + 0) * 72 + 2 * vkp] = (va.x & 0xFFFFu) | (vb2.x << 16);
            *(unsigned int*)&Vt[(vdg + 1) * 72 + 2 * vkp] = (va.x >> 16) | (vb2.x & 0xFFFF0000u);
            *(unsigned int*)&Vt[(vdg + 2) * 72 + 2 * vkp] = (va.y & 0xFFFFu) | (vb2.y << 16);
            *(unsigned int*)&Vt[(vdg + 3) * 72 + 2 * vkp] = (va.y >> 16) | (vb2.y & 0xFFFF0000u);
        }
        __syncthreads();

        // S = Q K^T : one MFMA per 16-key group
        const f32x4 zf = {};
        f32x4 sa0 = __builtin_amdgcn_mfma_f32_16x16x32_bf16(
            qf, *(const bf16x8*)&Ks[(0  + lq) * 40 + quad * 8], zf, 0, 0, 0);
        f32x4 sa1 = __builtin_amdgcn_mfma_f32_16x16x32_bf16(
            qf, *(const bf16x8*)&Ks[(16 + lq) * 40 + quad * 8], zf, 0, 0, 0);
        f32x4 sa2 = __builtin_amdgcn_mfma_f32_16x16x32_bf16(
            qf, *(const bf16x8*)&Ks[(32 + lq) * 40 + quad * 8], zf, 0, 0, 0);
        f32x4 sa3 = __builtin_amdgcn_mfma_f32_16x16x32_bf16(
            qf, *(const bf16x8*)&Ks[(48 + lq) * 40 + quad * 8], zf, 0, 0, 0);

        // p = exp2(qk*SC2 + sph*log2e); accumulate per-lane l; P -> LDS bf16
#pragma unroll
        for (int r = 0; r < 4; ++r) {
            float sb0, sb1, sb2, sb3;
            if (SPHB16) {
                const unsigned short* spr = spb + (size_t)r * 2048 + k0;
                sb0 = b2f(spr[0]);  sb1 = b2f(spr[16]);
                sb2 = b2f(spr[32]); sb3 = b2f(spr[48]);
            } else {
                const float* spr = spf + (size_t)r * 2048 + k0;
                sb0 = spr[0]  * LOG2E; sb1 = spr[16] * LOG2E;
                sb2 = spr[32] * LOG2E; sb3 = spr[48] * LOG2E;
            }
            const float p0 = __builtin_amdgcn_exp2f(fmaf(sa0[r], SC2, sb0));
            const float p1 = __builtin_amdgcn_exp2f(fmaf(sa1[r], SC2, sb1));
            const float p2 = __builtin_amdgcn_exp2f(fmaf(sa2[r], SC2, sb2));
            const float p3 = __builtin_amdgcn_exp2f(fmaf(sa3[r], SC2, sb3));
            l_r[r] += (p0 + p1) + (p2 + p3);
            unsigned short* pw = &Ps[wid][(quad * 4 + r) * 72 + lq];
            pw[0]  = f2b(p0);
            pw[16] = f2b(p1);
            pw[32] = f2b(p2);
            pw[48] = f2b(p3);
        }

        // PV: P from wave-private LDS slab, V^T as B
#pragma unroll
        for (int k2 = 0; k2 < 2; ++k2) {
            bf16x8 pf = *(const bf16x8*)&Ps[wid][lq * 72 + k2 * 32 + quad * 8];
            o0 = __builtin_amdgcn_mfma_f32_16x16x32_bf16(
                pf, *(const bf16x8*)&Vt[(0  + lq) * 72 + k2 * 32 + quad * 8], o0, 0, 0, 0);
            o1 = __builtin_amdgcn_mfma_f32_16x16x32_bf16(
                pf, *(const bf16x8*)&Vt[(16 + lq) * 72 + k2 * 32 + quad * 8], o1, 0, 0, 0);
        }
    }

    // epilogue: reduce l across the 16 lanes of each row group, O/l, store
    unsigned short* op = Ctx + (bS + q0 + wid * 16 + quad * 4) * 256 + h * 32;
#pragma unroll
    for (int r = 0; r < 4; ++r) {
        float l = l_r[r];
        l += __shfl_xor(l, 1);
        l += __shfl_xor(l, 2);
        l += __shfl_xor(l, 4);
        l += __shfl_xor(l, 8);
        const float inv = 1.f / l;
        op[r * 256 + lq]      = f2b(o0[r] * inv);
        op[r * 256 + 16 + lq] = f2b(o1[r] * inv);
    }
}

// ---------------- fused residual + LayerNorm (fp32 stream) ----------------
__global__ __launch_bounds__(256) void add_ln_kernel(
    const float* __restrict__ x, const unsigned short* __restrict__ r,
    const float* __restrict__ g, const float* __restrict__ be,
    float* __restrict__ out) {
    const int lane = threadIdx.x & 63, wid = threadIdx.x >> 6;
    const size_t row = (size_t)blockIdx.x * 4 + wid;
    float4 xv = *(const float4*)(x + row * 256 + lane * 4);
    uint2 ru = *(const uint2*)(r + row * 256 + lane * 4);
    float2 ra = bpair(ru.x), rb = bpair(ru.y);
    float v[4] = {xv.x + ra.x, xv.y + ra.y, xv.z + rb.x, xv.w + rb.y};
    float sum = v[0] + v[1] + v[2] + v[3];
#pragma unroll
    for (int off = 32; off; off >>= 1) sum += __shfl_xor(sum, off);
    const float mu = sum * (1.f / 256.f);
    float sq = 0.f;
#pragma unroll
    for (int i = 0; i < 4; i++) { float d = v[i] - mu; sq += d * d; }
#pragma unroll
    for (int off = 32; off; off >>= 1) sq += __shfl_xor(sq, off);
    const float rs = rsqrtf(sq * (1.f / 256.f) + 1e-5f);
    float4 o;
    o.x = (v[0] - mu) * rs * g[lane * 4 + 0] + be[lane * 4 + 0];
    o.y = (v[1] - mu) * rs * g[lane * 4 + 1] + be[lane * 4 + 1];
    o.z = (v[2] - mu) * rs * g[lane * 4 + 2] + be[lane * 4 + 2];
    o.w = (v[3] - mu) * rs * g[lane * 4 + 3] + be[lane * 4 + 3];
    *(float4*)(out + row * 256 + lane * 4) = o;
}

// ---------------- launch ----------------
extern "C" void kernel_launch(void* const* d_in, const int* in_sizes, int n_in,
                              void* d_out, int out_size, void* d_ws, size_t ws_size,
                              hipStream_t stream) {
    const float* src = (const float*)d_in[0];
    const float* sph = (const float*)d_in[1];
    const float* Wq  = (const float*)d_in[2];
    const float* bq  = (const float*)d_in[3];
    const float* Wk  = (const float*)d_in[4];
    const float* bk  = (const float*)d_in[5];
    const float* Wv  = (const float*)d_in[6];
    const float* bv  = (const float*)d_in[7];
    const float* Wo  = (const float*)d_in[8];
    const float* bo  = (const float*)d_in[9];
    const float* W1  = (const float*)d_in[10];
    const float* b1  = (const float*)d_in[11];
    const float* W2  = (const float*)d_in[12];
    const float* b2  = (const float*)d_in[13];
    const float* g1  = (const float*)d_in[14];
    const float* be1 = (const float*)d_in[15];
    const float* g2  = (const float*)d_in[16];
    const float* be2 = (const float*)d_in[17];

    char* ws = (char*)d_ws;
    float* X = (float*)d_out;                               // fp32 activations in d_out
    unsigned short* QKV = (unsigned short*)(ws + 0);        // 16384 x 768 bf16 (25.2MB)
    unsigned short* CTX = (unsigned short*)(ws + 25165824); // 16384 x 256
    unsigned short* T2  = (unsigned short*)(ws + 33554432);
    unsigned short* H   = QKV;                              // 16384x1024 bf16 reuses QKV+CTX
    unsigned short* WtQKV = (unsigned short*)(ws + 41943040); // 5 x 768 x 256
    unsigned short* WtO   = (unsigned short*)(ws + 43909120); // 5 x 256 x 256
    unsigned short* Wt1   = (unsigned short*)(ws + 44564480); // 5 x 1024 x 256
    unsigned short* Wt2   = (unsigned short*)(ws + 47185920); // 5 x 256 x 1024
    unsigned short* SPHB  = (unsigned short*)(ws + 50331648); // 8x2048x2048 bf16 (67MB)
    const int use_b16 = (ws_size >= (size_t)117440512);

    const dim3 tb(32, 8);
    transcvt_k<<<dim3(8, 8, 5),  tb, 0, stream>>>(Wq, WtQKV,          256, 256, 65536, 196608);
    transcvt_k<<<dim3(8, 8, 5),  tb, 0, stream>>>(Wk, WtQKV + 65536,  256, 256, 65536, 196608);
    transcvt_k<<<dim3(8, 8, 5),  tb, 0, stream>>>(Wv, WtQKV + 131072, 256, 256, 65536, 196608);
    transcvt_k<<<dim3(8, 8, 5),  tb, 0, stream>>>(Wo, WtO,            256, 256, 65536, 65536);
    transcvt_k<<<dim3(32, 8, 5), tb, 0, stream>>>(W1, Wt1,            256, 1024, 262144, 262144);
    transcvt_k<<<dim3(8, 32, 5), tb, 0, stream>>>(W2, Wt2,            1024, 256, 262144, 262144);
    if (use_b16) sph_cvt<<<16384, 256, 0, stream>>>(sph, SPHB);

    hipMemcpyAsync(X, src, 16777216, hipMemcpyDeviceToDevice, stream);

    const int M = 16384;
    for (int lyr = 0; lyr < 5; ++lyr) {
        gemm_bias_kernel<1, 1><<<dim3(12, 256), 256, 0, stream>>>(
            X, WtQKV + lyr * 196608, bq + lyr * 256, bk + lyr * 256, bv + lyr * 256,
            QKV, M, 768, 256, 0);
        if (use_b16)
            attn_mfma<1><<<2048, 256, 0, stream>>>(QKV, QKV + 256, QKV + 512, sph, SPHB, CTX);
        else
            attn_mfma<0><<<2048, 256, 0, stream>>>(QKV, QKV + 256, QKV + 512, sph, SPHB, CTX);
        gemm_bias_kernel<0, 0><<<dim3(4, 256), 256, 0, stream>>>(
            CTX, WtO + lyr * 65536, bo + lyr * 256, nullptr, nullptr, T2, M, 256, 256, 0);
        add_ln_kernel<<<4096, 256, 0, stream>>>(X, T2, g1 + lyr * 256, be1 + lyr * 256, X);
        gemm_bias_kernel<1, 0><<<dim3(16, 256), 256, 0, stream>>>(
            X, Wt1 + lyr * 262144, b1 + lyr * 1024, nullptr, nullptr, H, M, 1024, 256, 1);
        gemm_bias_kernel<0, 0><<<dim3(4, 256), 256, 0, stream>>>(
            H, Wt2 + lyr * 262144, b2 + lyr * 256, nullptr, nullptr, T2, M, 256, 1024, 0);
        add_ln_kernel<<<4096, 256, 0, stream>>>(X, T2, g2 + lyr * 256, be2 + lyr * 256, X);
    }
}